// Round 1
// baseline (22718.973 us; speedup 1.0000x reference)
//
#include <hip/hip_runtime.h>
#include <math.h>

#define BB 2
#define TT_SEQ 2048
#define NTOK (BB*TT_SEQ)   // 4096 tokens
#define DD 1024
#define VV 50257

#define TT 16              // tokens per block tile
#define VT 128             // vocab cols per subtile
#define KT 32              // k-tile
#define NSUB 8             // subtiles per chunk -> 1024 vocab per chunk
#define CHUNK (VT*NSUB)    // 1024
#define NCHUNK ((VV + CHUNK - 1)/CHUNK)   // 50
#define NTTILE (NTOK/TT)   // 256

// ---------------------------------------------------------------------------
// Kernel 1: label logits. One block per token: dot(X[t], E[label[t]]) + b.
// ---------------------------------------------------------------------------
__global__ __launch_bounds__(256) void ce_label(
    const float* __restrict__ X, const float* __restrict__ E,
    const float* __restrict__ bias, const int* __restrict__ labels,
    float* __restrict__ lab_out)
{
    int t = blockIdx.x;
    int lbl = labels[t];
    const float4* x = (const float4*)(X + (size_t)t * DD);
    const float4* e = (const float4*)(E + (size_t)lbl * DD);
    int i = threadIdx.x;              // DD/4 == 256 == blockDim
    float4 a = x[i], b4 = e[i];
    float s = a.x*b4.x + a.y*b4.y + a.z*b4.z + a.w*b4.w;
    #pragma unroll
    for (int off = 32; off; off >>= 1) s += __shfl_down(s, off, 64);
    __shared__ float red[4];
    if ((threadIdx.x & 63) == 0) red[threadIdx.x >> 6] = s;
    __syncthreads();
    if (threadIdx.x == 0)
        lab_out[t] = red[0] + red[1] + red[2] + red[3] + bias[lbl];
}

// ---------------------------------------------------------------------------
// Kernel 2: fused GEMM + online (max, sumexp) per (token, vocab-chunk).
// Block = 256 threads, tile TT=16 tokens x VT=128 vocab, NSUB=8 subtiles.
// Thread (ty = tid>>4, tx = tid&15) owns token ty, cols tx+16*c (c=0..7).
// ---------------------------------------------------------------------------
__global__ __launch_bounds__(256) void ce_partial(
    const float* __restrict__ X, const float* __restrict__ E,
    const float* __restrict__ bias, float* __restrict__ pairs)
{
    int ttile = blockIdx.x;           // fast-varying -> L2 locality on E chunk
    int chunk = blockIdx.y;
    int tid = threadIdx.x;
    int ty = tid >> 4;                // 0..15 token row
    int tx = tid & 15;                // col group

    __shared__ float As[TT][KT + 1];  // +1 pad: conflict-free
    __shared__ float Bs[VT][KT + 1];

    int tok0 = ttile * TT;
    float run_m = -INFINITY, run_s = 0.f;

    for (int sub = 0; sub < NSUB; ++sub) {
        int v0 = chunk * CHUNK + sub * VT;
        float acc[8];
        #pragma unroll
        for (int c = 0; c < 8; ++c) acc[c] = 0.f;

        for (int k0 = 0; k0 < DD; k0 += KT) {
            __syncthreads();
            // stage A: 16x32 floats; thread loads float2 at (ty, 2*tx)
            {
                const float2 a2 = *(const float2*)(X + (size_t)(tok0 + ty) * DD + k0 + 2 * tx);
                As[ty][2 * tx]     = a2.x;
                As[ty][2 * tx + 1] = a2.y;
            }
            // stage B: 128x32 floats = 1024 float4; 4 float4 per thread
            #pragma unroll
            for (int j = 0; j < 4; ++j) {
                int idx = tid + 256 * j;
                int r  = idx >> 3;           // 0..127
                int c4 = (idx & 7) << 2;     // 0,4,...,28
                int v = v0 + r;
                float4 b4 = make_float4(0.f, 0.f, 0.f, 0.f);
                if (v < VV)
                    b4 = *(const float4*)(E + (size_t)v * DD + k0 + c4);
                Bs[r][c4]     = b4.x;
                Bs[r][c4 + 1] = b4.y;
                Bs[r][c4 + 2] = b4.z;
                Bs[r][c4 + 3] = b4.w;
            }
            __syncthreads();
            #pragma unroll
            for (int k = 0; k < KT; ++k) {
                float a = As[ty][k];
                #pragma unroll
                for (int c = 0; c < 8; ++c)
                    acc[c] += a * Bs[tx + 16 * c][k];
            }
        }

        // bias + mask + online (m,s) update
        float lv[8];
        float lm = -INFINITY;
        #pragma unroll
        for (int c = 0; c < 8; ++c) {
            int v = v0 + tx + 16 * c;
            float lg = (v < VV) ? acc[c] + bias[v] : -INFINITY;
            lv[c] = lg;
            lm = fmaxf(lm, lg);
        }
        if (lm != -INFINITY) {
            float nm = fmaxf(run_m, lm);
            float s = run_s * expf(run_m - nm);   // run_m=-inf -> 0*0=0, ok
            #pragma unroll
            for (int c = 0; c < 8; ++c) s += expf(lv[c] - nm);  // -inf -> 0
            run_m = nm; run_s = s;
        }
    }

    // reduce (m,s) across the 16 lanes of this token's tx-group
    #pragma unroll
    for (int off = 1; off < 16; off <<= 1) {
        float om = __shfl_xor(run_m, off, 64);
        float os = __shfl_xor(run_s, off, 64);
        if (os > 0.f) {
            if (om > run_m) { run_s = run_s * expf(run_m - om) + os; run_m = om; }
            else           { run_s += os * expf(om - run_m); }
        }
    }
    if (tx == 0) {
        size_t o = ((size_t)chunk * NTOK + tok0 + ty) * 2;
        pairs[o]     = run_m;
        pairs[o + 1] = run_s;
    }
}

// ---------------------------------------------------------------------------
// Kernel 3: combine chunks per token, subtract label logit, mean -> out[0].
// Single block, single deterministic write (no init of d_out needed).
// ---------------------------------------------------------------------------
__global__ __launch_bounds__(256) void ce_final(
    const float* __restrict__ pairs, const float* __restrict__ lab,
    float* __restrict__ out)
{
    int tid = threadIdx.x;
    float acc = 0.f;
    for (int t = tid; t < NTOK; t += 256) {
        float M = -INFINITY, S = 0.f;
        for (int c = 0; c < NCHUNK; ++c) {
            size_t o = ((size_t)c * NTOK + t) * 2;
            float m = pairs[o], s = pairs[o + 1];
            if (s > 0.f) {
                if (m > M) { S = S * expf(M - m) + s; M = m; }
                else       { S += s * expf(m - M); }
            }
        }
        acc += (M + logf(S)) - lab[t];
    }
    #pragma unroll
    for (int off = 32; off; off >>= 1) acc += __shfl_down(acc, off, 64);
    __shared__ float red[4];
    if ((tid & 63) == 0) red[tid >> 6] = acc;
    __syncthreads();
    if (tid == 0)
        out[0] = (red[0] + red[1] + red[2] + red[3]) / (float)NTOK;
}

extern "C" void kernel_launch(void* const* d_in, const int* in_sizes, int n_in,
                              void* d_out, int out_size, void* d_ws, size_t ws_size,
                              hipStream_t stream) {
    const float* X    = (const float*)d_in[0];   // [4096,1024]
    const float* E    = (const float*)d_in[1];   // [50257,1024]
    const float* bias = (const float*)d_in[2];   // [50257]
    const int*   labels = (const int*)d_in[3];   // [4096]
    float* out = (float*)d_out;

    float* ws    = (float*)d_ws;
    float* lab   = ws;           // 4096 floats
    float* pairs = ws + NTOK;    // NCHUNK*4096*2 floats (~1.6 MB)

    ce_label<<<NTOK, 256, 0, stream>>>(X, E, bias, labels, lab);
    dim3 grid(NTTILE, NCHUNK);
    ce_partial<<<grid, 256, 0, stream>>>(X, E, bias, pairs);
    ce_final<<<1, 256, 0, stream>>>(pairs, lab, out);
}

// Round 2
// 845.393 us; speedup vs baseline: 26.8739x; 26.8739x over previous
//
#include <hip/hip_runtime.h>
#include <math.h>

#define NTOK 4096
#define DD   1024
#define VV   50257

// ---- fast (MFMA) path geometry ----
#define BM      128                 // tokens per block
#define BNSUB   128                 // vocab per subtile
#define NSUB    4
#define CHUNKV  512                 // vocab per block (chunk)
#define NCHUNK2 99                  // ceil(50257/512)
#define VPAD    (NCHUNK2*CHUNKV)    // 50688 padded vocab rows
#define NTTILE2 (NTOK/BM)           // 32
#define LOG2E   1.4426950408889634f
#define LN2F    0.6931471805599453f

// ---- fallback (round-1 fp32) path geometry ----
#define TT 16
#define VT 128
#define KT 32
#define NSUB_O 8
#define CHUNK_O (VT*NSUB_O)
#define NCHUNK_O ((VV + CHUNK_O - 1)/CHUNK_O)
#define NTTILE_O (NTOK/TT)

typedef __attribute__((ext_vector_type(8))) __bf16 bf16x8;
typedef __attribute__((ext_vector_type(4))) float  f32x4;

__device__ __forceinline__ unsigned short f2bf(float f) {
    unsigned u = __float_as_uint(f);
    unsigned r = (u + 0x7FFFu + ((u >> 16) & 1u)) >> 16;   // RTNE
    return (unsigned short)r;
}

__device__ __forceinline__ void gload16(const void* g, void* l) {
    __builtin_amdgcn_global_load_lds(
        (const __attribute__((address_space(1))) void*)g,
        (__attribute__((address_space(3))) void*)l, 16, 0, 0);
}

// ---------------------------------------------------------------------------
// fp32 -> bf16 conversion of X (one float4 per thread)
// ---------------------------------------------------------------------------
__global__ __launch_bounds__(256) void convX(const float* __restrict__ X,
                                             unsigned short* __restrict__ Xb) {
    int i = blockIdx.x * 256 + threadIdx.x;        // float4 index
    float4 v = ((const float4*)X)[i];
    ushort4 o;
    o.x = f2bf(v.x); o.y = f2bf(v.y); o.z = f2bf(v.z); o.w = f2bf(v.w);
    ((ushort4*)Xb)[i] = o;
}

// fp32 -> bf16 conversion of E with zero-padding to VPAD rows (block = 1 row)
__global__ __launch_bounds__(256) void convE(const float* __restrict__ E,
                                             unsigned short* __restrict__ Eb) {
    int row = blockIdx.x;                          // 0..VPAD-1
    int t = threadIdx.x;                           // 256 threads x float4 = 1024
    float4 v = make_float4(0.f, 0.f, 0.f, 0.f);
    if (row < VV) v = ((const float4*)(E + (size_t)row * DD))[t];
    ushort4 o;
    o.x = f2bf(v.x); o.y = f2bf(v.y); o.z = f2bf(v.z); o.w = f2bf(v.w);
    ((ushort4*)(Eb + (size_t)row * DD))[t] = o;
}

// ---------------------------------------------------------------------------
// Label logits in fp32 (exact). One block per token.
// ---------------------------------------------------------------------------
__global__ __launch_bounds__(256) void ce_label(
    const float* __restrict__ X, const float* __restrict__ E,
    const float* __restrict__ bias, const int* __restrict__ labels,
    float* __restrict__ lab_out)
{
    int t = blockIdx.x;
    int lbl = labels[t];
    const float4* x = (const float4*)(X + (size_t)t * DD);
    const float4* e = (const float4*)(E + (size_t)lbl * DD);
    int i = threadIdx.x;
    float4 a = x[i], b4 = e[i];
    float s = a.x*b4.x + a.y*b4.y + a.z*b4.z + a.w*b4.w;
    #pragma unroll
    for (int off = 32; off; off >>= 1) s += __shfl_down(s, off, 64);
    __shared__ float red[4];
    if ((threadIdx.x & 63) == 0) red[threadIdx.x >> 6] = s;
    __syncthreads();
    if (threadIdx.x == 0)
        lab_out[t] = red[0] + red[1] + red[2] + red[3] + bias[lbl];
}

// ---------------------------------------------------------------------------
// Fused bf16-MFMA GEMM + online (max, sumexp) per (128-token, 512-vocab chunk).
// 256 threads = 4 waves in a 2x2 grid; each wave owns 64x64 of the 128x128
// subtile via 4x4 16x16x32 fragments. Per-lane running (m,s) in base-2 over
// the 16-col group it owns; one cross-lane merge per chunk.
// ---------------------------------------------------------------------------
__global__ __launch_bounds__(256) void ce_mfma(
    const unsigned short* __restrict__ Xb, const unsigned short* __restrict__ Eb,
    const float* __restrict__ bias, float* __restrict__ pairs)
{
    __shared__ unsigned short As[BM * 32];      // 8 KB, swizzled 16B slots
    __shared__ unsigned short Bs[BNSUB * 32];   // 8 KB

    const int tid  = threadIdx.x;
    const int lane = tid & 63;
    const int wave = tid >> 6;
    const int wy = wave >> 1, wx = wave & 1;
    const int ttile = blockIdx.x, chunk = blockIdx.y;
    const int tok0 = ttile * BM;
    const int khalf = (lane >> 4) & 3;
    const int cl = lane & 15;

    // staging: linear 16B slot s = j*256 + tid holds (row=s>>2, kdata=(s&3)^((row>>1)&3))
    const int s0 = tid,        r0 = s0 >> 2, kd0 = (s0 & 3) ^ ((r0 >> 1) & 3);
    const int s1 = 256 + tid,  r1 = s1 >> 2, kd1 = (s1 & 3) ^ ((r1 >> 1) & 3);
    char* AsB = (char*)As;
    char* BsB = (char*)Bs;
    char* ldsA0 = AsB + wave * 1024;
    char* ldsA1 = AsB + 4096 + wave * 1024;
    char* ldsB0 = BsB + wave * 1024;
    char* ldsB1 = BsB + 4096 + wave * 1024;

    float run_m[16], run_s[16];
    #pragma unroll
    for (int i = 0; i < 16; ++i) { run_m[i] = -INFINITY; run_s[i] = 0.f; }

    const unsigned short* Abase = Xb + (size_t)tok0 * DD;

    for (int sub = 0; sub < NSUB; ++sub) {
        const int v0 = chunk * CHUNKV + sub * BNSUB;
        const unsigned short* Bbase = Eb + (size_t)v0 * DD;

        f32x4 acc[4][4];
        #pragma unroll
        for (int mi = 0; mi < 4; ++mi)
            #pragma unroll
            for (int ni = 0; ni < 4; ++ni)
                acc[mi][ni] = (f32x4){0.f, 0.f, 0.f, 0.f};

        for (int k0 = 0; k0 < DD; k0 += 32) {
            __syncthreads();
            gload16(Abase + (size_t)r0 * DD + k0 + kd0 * 8, ldsA0);
            gload16(Abase + (size_t)r1 * DD + k0 + kd1 * 8, ldsA1);
            gload16(Bbase + (size_t)r0 * DD + k0 + kd0 * 8, ldsB0);
            gload16(Bbase + (size_t)r1 * DD + k0 + kd1 * 8, ldsB1);
            __syncthreads();

            bf16x8 af[4], bfr[4];
            #pragma unroll
            for (int mi = 0; mi < 4; ++mi) {
                int row = wy * 64 + mi * 16 + cl;
                int slot = row * 4 + (khalf ^ ((row >> 1) & 3));
                af[mi] = *(const bf16x8*)(AsB + slot * 16);
            }
            #pragma unroll
            for (int ni = 0; ni < 4; ++ni) {
                int row = wx * 64 + ni * 16 + cl;
                int slot = row * 4 + (khalf ^ ((row >> 1) & 3));
                bfr[ni] = *(const bf16x8*)(BsB + slot * 16);
            }
            #pragma unroll
            for (int mi = 0; mi < 4; ++mi)
                #pragma unroll
                for (int ni = 0; ni < 4; ++ni)
                    acc[mi][ni] = __builtin_amdgcn_mfma_f32_16x16x32_bf16(
                        af[mi], bfr[ni], acc[mi][ni], 0, 0, 0);
        }

        // epilogue: bias + base-2 online (m,s) update, per-lane 16-col group
        const int cb = v0 + wx * 64 + cl;
        float bv[4]; bool msk[4];
        #pragma unroll
        for (int ni = 0; ni < 4; ++ni) {
            int v = cb + ni * 16;
            msk[ni] = (v < VV);
            bv[ni] = msk[ni] ? bias[v] : 0.f;
        }
        #pragma unroll
        for (int mi = 0; mi < 4; ++mi) {
            #pragma unroll
            for (int r = 0; r < 4; ++r) {
                float l0 = msk[0] ? (acc[mi][0][r] + bv[0]) * LOG2E : -INFINITY;
                float l1 = msk[1] ? (acc[mi][1][r] + bv[1]) * LOG2E : -INFINITY;
                float l2 = msk[2] ? (acc[mi][2][r] + bv[2]) * LOG2E : -INFINITY;
                float l3 = msk[3] ? (acc[mi][3][r] + bv[3]) * LOG2E : -INFINITY;
                float vm = fmaxf(fmaxf(l0, l1), fmaxf(l2, l3));
                if (vm > -INFINITY) {
                    const int i = mi * 4 + r;
                    float nm = fmaxf(run_m[i], vm);
                    float s = run_s[i] * exp2f(run_m[i] - nm);
                    s += exp2f(l0 - nm) + exp2f(l1 - nm) + exp2f(l2 - nm) + exp2f(l3 - nm);
                    run_m[i] = nm; run_s[i] = s;
                }
            }
        }
    }

    // cross-lane merge over the 16-lane column groups
    #pragma unroll
    for (int i = 0; i < 16; ++i) {
        float m = run_m[i], s = run_s[i];
        #pragma unroll
        for (int off = 1; off < 16; off <<= 1) {
            float om = __shfl_xor(m, off, 64);
            float os = __shfl_xor(s, off, 64);
            if (os > 0.f) {
                if (om > m) { s = s * exp2f(m - om) + os; m = om; }
                else        { s += os * exp2f(om - m); }
            }
        }
        run_m[i] = m; run_s[i] = s;
    }

    if (cl == 0) {
        const int trow_base = tok0 + wy * 64 + (lane >> 4) * 4;
        const size_t pbase = (size_t)(chunk * 2 + wx) * NTOK;
        #pragma unroll
        for (int mi = 0; mi < 4; ++mi)
            #pragma unroll
            for (int r = 0; r < 4; ++r) {
                int t = trow_base + mi * 16 + r;
                size_t o = (pbase + t) * 2;
                pairs[o]     = run_m[mi * 4 + r];
                pairs[o + 1] = run_s[mi * 4 + r];
            }
    }
}

// ---------------------------------------------------------------------------
// Combine 198 partial (m,s) pairs per token -> per-block loss partial sums
// ---------------------------------------------------------------------------
__global__ __launch_bounds__(256) void ce_combine(
    const float* __restrict__ pairs, const float* __restrict__ lab,
    float* __restrict__ partials)
{
    int t = blockIdx.x * 256 + threadIdx.x;    // token, grid 16 x 256 = 4096
    float M = -INFINITY, S = 0.f;
    for (int c = 0; c < NCHUNK2 * 2; ++c) {
        size_t o = ((size_t)c * NTOK + t) * 2;
        float m = pairs[o], s = pairs[o + 1];
        if (s > 0.f) {
            if (m > M) { S = S * exp2f(M - m) + s; M = m; }
            else       { S += s * exp2f(m - M); }
        }
    }
    float acc = (M + log2f(S)) * LN2F - lab[t];
    #pragma unroll
    for (int off = 32; off; off >>= 1) acc += __shfl_down(acc, off, 64);
    __shared__ float red[4];
    if ((threadIdx.x & 63) == 0) red[threadIdx.x >> 6] = acc;
    __syncthreads();
    if (threadIdx.x == 0)
        partials[blockIdx.x] = red[0] + red[1] + red[2] + red[3];
}

__global__ void ce_sum(const float* __restrict__ partials, float* __restrict__ out) {
    if (threadIdx.x == 0) {
        float s = 0.f;
        for (int i = 0; i < 16; ++i) s += partials[i];
        out[0] = s / (float)NTOK;
    }
}

// ---------------------------------------------------------------------------
// FALLBACK path (round-1 fp32 kernels) — used only if ws_size is too small
// ---------------------------------------------------------------------------
__global__ __launch_bounds__(256) void ce_partial_old(
    const float* __restrict__ X, const float* __restrict__ E,
    const float* __restrict__ bias, float* __restrict__ pairs)
{
    int ttile = blockIdx.x;
    int chunk = blockIdx.y;
    int tid = threadIdx.x;
    int ty = tid >> 4;
    int tx = tid & 15;

    __shared__ float As_[TT][KT + 1];
    __shared__ float Bs_[VT][KT + 1];

    int tok0 = ttile * TT;
    float run_m = -INFINITY, run_s = 0.f;

    for (int sub = 0; sub < NSUB_O; ++sub) {
        int v0 = chunk * CHUNK_O + sub * VT;
        float acc[8];
        #pragma unroll
        for (int c = 0; c < 8; ++c) acc[c] = 0.f;

        for (int k0 = 0; k0 < DD; k0 += KT) {
            __syncthreads();
            {
                const float2 a2 = *(const float2*)(X + (size_t)(tok0 + ty) * DD + k0 + 2 * tx);
                As_[ty][2 * tx]     = a2.x;
                As_[ty][2 * tx + 1] = a2.y;
            }
            #pragma unroll
            for (int j = 0; j < 4; ++j) {
                int idx = tid + 256 * j;
                int r  = idx >> 3;
                int c4 = (idx & 7) << 2;
                int v = v0 + r;
                float4 b4 = make_float4(0.f, 0.f, 0.f, 0.f);
                if (v < VV)
                    b4 = *(const float4*)(E + (size_t)v * DD + k0 + c4);
                Bs_[r][c4]     = b4.x;
                Bs_[r][c4 + 1] = b4.y;
                Bs_[r][c4 + 2] = b4.z;
                Bs_[r][c4 + 3] = b4.w;
            }
            __syncthreads();
            #pragma unroll
            for (int k = 0; k < KT; ++k) {
                float a = As_[ty][k];
                #pragma unroll
                for (int c = 0; c < 8; ++c)
                    acc[c] += a * Bs_[tx + 16 * c][k];
            }
        }

        float lv[8];
        float lm = -INFINITY;
        #pragma unroll
        for (int c = 0; c < 8; ++c) {
            int v = v0 + tx + 16 * c;
            float lg = (v < VV) ? acc[c] + bias[v] : -INFINITY;
            lv[c] = lg;
            lm = fmaxf(lm, lg);
        }
        if (lm != -INFINITY) {
            float nm = fmaxf(run_m, lm);
            float s = run_s * expf(run_m - nm);
            #pragma unroll
            for (int c = 0; c < 8; ++c) s += expf(lv[c] - nm);
            run_m = nm; run_s = s;
        }
    }

    #pragma unroll
    for (int off = 1; off < 16; off <<= 1) {
        float om = __shfl_xor(run_m, off, 64);
        float os = __shfl_xor(run_s, off, 64);
        if (os > 0.f) {
            if (om > run_m) { run_s = run_s * expf(run_m - om) + os; run_m = om; }
            else            { run_s += os * expf(om - run_m); }
        }
    }
    if (tx == 0) {
        size_t o = ((size_t)chunk * NTOK + tok0 + ty) * 2;
        pairs[o]     = run_m;
        pairs[o + 1] = run_s;
    }
}

__global__ __launch_bounds__(256) void ce_final_old(
    const float* __restrict__ pairs, const float* __restrict__ lab,
    float* __restrict__ out)
{
    int tid = threadIdx.x;
    float acc = 0.f;
    for (int t = tid; t < NTOK; t += 256) {
        float M = -INFINITY, S = 0.f;
        for (int c = 0; c < NCHUNK_O; ++c) {
            size_t o = ((size_t)c * NTOK + t) * 2;
            float m = pairs[o], s = pairs[o + 1];
            if (s > 0.f) {
                if (m > M) { S = S * expf(M - m) + s; M = m; }
                else       { S += s * expf(m - M); }
            }
        }
        acc += (M + logf(S)) - lab[t];
    }
    #pragma unroll
    for (int off = 32; off; off >>= 1) acc += __shfl_down(acc, off, 64);
    __shared__ float red[4];
    if ((tid & 63) == 0) red[tid >> 6] = acc;
    __syncthreads();
    if (tid == 0)
        out[0] = (red[0] + red[1] + red[2] + red[3]) / (float)NTOK;
}

// ---------------------------------------------------------------------------
extern "C" void kernel_launch(void* const* d_in, const int* in_sizes, int n_in,
                              void* d_out, int out_size, void* d_ws, size_t ws_size,
                              hipStream_t stream) {
    const float* X      = (const float*)d_in[0];   // [4096,1024]
    const float* E      = (const float*)d_in[1];   // [50257,1024]
    const float* bias   = (const float*)d_in[2];   // [50257]
    const int*   labels = (const int*)d_in[3];     // [4096]
    float* out = (float*)d_out;

    char* ws = (char*)d_ws;
    const size_t off_lab   = 0;                                        // 16 KB
    const size_t off_pairs = 16384;
    const size_t sz_pairs  = (size_t)NCHUNK2 * 2 * NTOK * 2 * 4;       // ~12.4 MB
    const size_t off_part  = off_pairs + sz_pairs;
    const size_t off_Xb    = off_part + 1024;                          // align
    const size_t off_Eb    = off_Xb + (size_t)NTOK * DD * 2;
    const size_t need      = off_Eb + (size_t)VPAD * DD * 2;           // ~119 MB

    float* lab = (float*)(ws + off_lab);

    if (ws_size >= need) {
        unsigned short* Xb = (unsigned short*)(ws + off_Xb);
        unsigned short* Eb = (unsigned short*)(ws + off_Eb);
        float* pairs    = (float*)(ws + off_pairs);
        float* partials = (float*)(ws + off_part);

        convX<<<NTOK * DD / 1024, 256, 0, stream>>>(X, Xb);
        convE<<<VPAD, 256, 0, stream>>>(E, Eb);
        ce_label<<<NTOK, 256, 0, stream>>>(X, E, bias, labels, lab);
        dim3 grid(NTTILE2, NCHUNK2);
        ce_mfma<<<grid, 256, 0, stream>>>(Xb, Eb, bias, pairs);
        ce_combine<<<16, 256, 0, stream>>>(pairs, lab, partials);
        ce_sum<<<1, 64, 0, stream>>>(partials, out);
    } else {
        float* pairs = (float*)(ws + 16384);
        ce_label<<<NTOK, 256, 0, stream>>>(X, E, bias, labels, lab);
        dim3 grid(NTTILE_O, NCHUNK_O);
        ce_partial_old<<<grid, 256, 0, stream>>>(X, E, bias, pairs);
        ce_final_old<<<1, 256, 0, stream>>>(pairs, lab, out);
    }
}

// Round 3
// 465.721 us; speedup vs baseline: 48.7824x; 1.8152x over previous
//
#include <hip/hip_runtime.h>
#include <math.h>

#define NTOK 4096
#define DD   1024
#define VV   50257

#define LOG2E 1.4426950408889634f
#define LN2F  0.6931471805599453f

// ---- fast (MFMA, 256x256 pipelined) path geometry ----
#define BM   256
#define BN   256
#define BK   64
#define NKT  (DD/BK)          // 16 K-tiles
#define NC   197              // ceil(50257/256)
#define VPAD (NC*BN)          // 50432 padded vocab rows
#define NMT  (NTOK/BM)        // 16 token tiles

// ---- fallback (round-1 fp32) path geometry ----
#define TT 16
#define VT 128
#define KT 32
#define NSUB_O 8
#define CHUNK_O (VT*NSUB_O)
#define NCHUNK_O ((VV + CHUNK_O - 1)/CHUNK_O)
#define NTTILE_O (NTOK/TT)

typedef __attribute__((ext_vector_type(8))) __bf16 bf16x8;
typedef __attribute__((ext_vector_type(4))) float  f32x4;

__device__ __forceinline__ unsigned short f2bf(float f) {
    unsigned u = __float_as_uint(f);
    unsigned r = (u + 0x7FFFu + ((u >> 16) & 1u)) >> 16;   // RTNE
    return (unsigned short)r;
}

__device__ __forceinline__ void gload16(const void* g, void* l) {
    __builtin_amdgcn_global_load_lds(
        (const __attribute__((address_space(1))) void*)g,
        (__attribute__((address_space(3))) void*)l, 16, 0, 0);
}

// ---------------------------------------------------------------------------
// fp32 -> bf16 conversion of X (one float4 per thread)
// ---------------------------------------------------------------------------
__global__ __launch_bounds__(256) void convX(const float* __restrict__ X,
                                             unsigned short* __restrict__ Xb) {
    int i = blockIdx.x * 256 + threadIdx.x;        // float4 index
    float4 v = ((const float4*)X)[i];
    ushort4 o;
    o.x = f2bf(v.x); o.y = f2bf(v.y); o.z = f2bf(v.z); o.w = f2bf(v.w);
    ((ushort4*)Xb)[i] = o;
}

// fp32 -> bf16 conversion of E with zero-padding to VPAD rows (block = 1 row)
__global__ __launch_bounds__(256) void convE(const float* __restrict__ E,
                                             unsigned short* __restrict__ Eb) {
    int row = blockIdx.x;                          // 0..VPAD-1
    int t = threadIdx.x;                           // 256 threads x float4 = 1024
    float4 v = make_float4(0.f, 0.f, 0.f, 0.f);
    if (row < VV) v = ((const float4*)(E + (size_t)row * DD))[t];
    ushort4 o;
    o.x = f2bf(v.x); o.y = f2bf(v.y); o.z = f2bf(v.z); o.w = f2bf(v.w);
    ((ushort4*)(Eb + (size_t)row * DD))[t] = o;
}

// ---------------------------------------------------------------------------
// Label logits in fp32 (exact). One block per token.
// ---------------------------------------------------------------------------
__global__ __launch_bounds__(256) void ce_label(
    const float* __restrict__ X, const float* __restrict__ E,
    const float* __restrict__ bias, const int* __restrict__ labels,
    float* __restrict__ lab_out)
{
    int t = blockIdx.x;
    int lbl = labels[t];
    const float4* x = (const float4*)(X + (size_t)t * DD);
    const float4* e = (const float4*)(E + (size_t)lbl * DD);
    int i = threadIdx.x;
    float4 a = x[i], b4 = e[i];
    float s = a.x*b4.x + a.y*b4.y + a.z*b4.z + a.w*b4.w;
    #pragma unroll
    for (int off = 32; off; off >>= 1) s += __shfl_down(s, off, 64);
    __shared__ float red[4];
    if ((threadIdx.x & 63) == 0) red[threadIdx.x >> 6] = s;
    __syncthreads();
    if (threadIdx.x == 0)
        lab_out[t] = red[0] + red[1] + red[2] + red[3] + bias[lbl];
}

// ---------------------------------------------------------------------------
// Fused bf16-MFMA GEMM (256x256 tile, BK=64, dbuf LDS, early-issue staging)
// + fixed-max sum-of-exp epilogue. 512 threads = 8 waves (2 M-halves x 4
// N-quarters), each wave owns a 128x64 output tile = acc[8][4] f32x4.
// LDS per buffer: A[256][64] bf16 (32KB, XOR-swizzled 16B slots) + B same.
// Per K-tile: issue 8 global_load_lds for tile t+1 FIRST, then ds_read frags
// of tile t + 64 MFMA, then the single __syncthreads (vmcnt drain ~600cyc
// after issue -> latency hidden under compute).
// ---------------------------------------------------------------------------
__global__ __launch_bounds__(512, 2) void ce_mfma256(
    const unsigned short* __restrict__ Xb, const unsigned short* __restrict__ Eb,
    const float* __restrict__ bias, float* __restrict__ pairs)
{
    __shared__ char lds[131072];    // 2 x (A 32KB + B 32KB)

    const int tid   = threadIdx.x;
    const int lane  = tid & 63;
    const int w     = tid >> 6;      // 0..7
    const int wr    = w >> 2;        // 0..1  M half
    const int wc    = w & 3;         // 0..3  N quarter
    const int khalf = lane >> 4;     // 0..3
    const int cl    = lane & 15;
    const int c7    = cl & 7;

    const int mt   = blockIdx.x;     // 0..15
    const int nc   = blockIdx.y;     // 0..196
    const int tok0 = mt * BM;
    const int v0   = nc * BN;

    // staging: linear slot s = tid + 512*j holds global (row=s>>3, kgrp=(s&7)^(row&7))
    int soff[4]; unsigned stA[4], stB[4];
    #pragma unroll
    for (int j = 0; j < 4; ++j) {
        int s = tid + 512 * j;
        int r = s >> 3;
        int g = (s & 7) ^ (r & 7);
        soff[j] = r * DD + g * 8;                    // element offset
        stA[j]  = (unsigned)(w * 64 + 512 * j) * 16; // wave-uniform LDS base (bytes)
        stB[j]  = 32768u + stA[j];
    }
    const unsigned short* Asrc = Xb + (size_t)tok0 * DD;
    const unsigned short* Bsrc = Eb + (size_t)v0 * DD;

    f32x4 acc[8][4];
    #pragma unroll
    for (int mi = 0; mi < 8; ++mi)
        #pragma unroll
        for (int ni = 0; ni < 4; ++ni)
            acc[mi][ni] = (f32x4){0.f, 0.f, 0.f, 0.f};

    // prologue: stage K-tile 0 into buffer 0
    #pragma unroll
    for (int j = 0; j < 4; ++j) {
        gload16(Asrc + soff[j], lds + stA[j]);
        gload16(Bsrc + soff[j], lds + stB[j]);
    }
    __syncthreads();

    const int xg0 = (khalf ^ c7) * 16;         // kk=0 swizzled slot byte offset
    const int xg1 = ((4 + khalf) ^ c7) * 16;   // kk=1

    #pragma unroll 2
    for (int t = 0; t < NKT; ++t) {
        const int p = t & 1;
        // ---- issue next-tile staging FIRST (flies under the MFMAs below) ----
        if (t + 1 < NKT) {
            const unsigned bufn = (unsigned)(p ^ 1) * 65536u;
            const int ko = (t + 1) * BK;
            #pragma unroll
            for (int j = 0; j < 4; ++j) {
                gload16(Asrc + soff[j] + ko, lds + bufn + stA[j]);
                gload16(Bsrc + soff[j] + ko, lds + bufn + stB[j]);
            }
        }

        const char* pAb = lds + p * 65536 + (wr * 128 + cl) * 128;
        const char* pBb = lds + p * 65536 + 32768 + (wc * 64 + cl) * 128;
        const char* pA0 = pAb + xg0; const char* pA1 = pAb + xg1;
        const char* pB0 = pBb + xg0; const char* pB1 = pBb + xg1;

        bf16x8 bfr[4][2];
        #pragma unroll
        for (int ni = 0; ni < 4; ++ni) {
            bfr[ni][0] = *(const bf16x8*)(pB0 + ni * 2048);
            bfr[ni][1] = *(const bf16x8*)(pB1 + ni * 2048);
        }
        bf16x8 af[4][2];
        // ---- phase 0: mi 0..3 ----
        #pragma unroll
        for (int mi = 0; mi < 4; ++mi) {
            af[mi][0] = *(const bf16x8*)(pA0 + mi * 2048);
            af[mi][1] = *(const bf16x8*)(pA1 + mi * 2048);
        }
        __builtin_amdgcn_s_setprio(1);
        #pragma unroll
        for (int mi = 0; mi < 4; ++mi)
            #pragma unroll
            for (int ni = 0; ni < 4; ++ni) {
                acc[mi][ni] = __builtin_amdgcn_mfma_f32_16x16x32_bf16(
                    af[mi][0], bfr[ni][0], acc[mi][ni], 0, 0, 0);
                acc[mi][ni] = __builtin_amdgcn_mfma_f32_16x16x32_bf16(
                    af[mi][1], bfr[ni][1], acc[mi][ni], 0, 0, 0);
            }
        __builtin_amdgcn_s_setprio(0);
        // ---- phase 1: mi 4..7 ----
        #pragma unroll
        for (int mi = 0; mi < 4; ++mi) {
            af[mi][0] = *(const bf16x8*)(pA0 + (mi + 4) * 2048);
            af[mi][1] = *(const bf16x8*)(pA1 + (mi + 4) * 2048);
        }
        __builtin_amdgcn_s_setprio(1);
        #pragma unroll
        for (int mi = 0; mi < 4; ++mi)
            #pragma unroll
            for (int ni = 0; ni < 4; ++ni) {
                acc[mi + 4][ni] = __builtin_amdgcn_mfma_f32_16x16x32_bf16(
                    af[mi][0], bfr[ni][0], acc[mi + 4][ni], 0, 0, 0);
                acc[mi + 4][ni] = __builtin_amdgcn_mfma_f32_16x16x32_bf16(
                    af[mi][1], bfr[ni][1], acc[mi + 4][ni], 0, 0, 0);
            }
        __builtin_amdgcn_s_setprio(0);

        __syncthreads();   // single drain+barrier per K-tile: buf p^1 ready
    }

    // ---- epilogue: fixed-max sum of exp (base-2), masked pad cols ----
    float bb[4];
    #pragma unroll
    for (int ni = 0; ni < 4; ++ni) {
        int v = v0 + wc * 64 + ni * 16 + cl;
        bb[ni] = (v < VV) ? bias[v] * LOG2E : -INFINITY;
    }
    float run[32];
    #pragma unroll
    for (int i = 0; i < 32; ++i) run[i] = 0.f;
    #pragma unroll
    for (int mi = 0; mi < 8; ++mi)
        #pragma unroll
        for (int ni = 0; ni < 4; ++ni)
            #pragma unroll
            for (int r = 0; r < 4; ++r)
                run[mi * 4 + r] += exp2f(fmaf(acc[mi][ni][r], LOG2E, bb[ni]));

    // reduce across the 16 lanes (cl) of each khalf group
    #pragma unroll
    for (int i = 0; i < 32; ++i) {
        float s = run[i];
        s += __shfl_xor(s, 1); s += __shfl_xor(s, 2);
        s += __shfl_xor(s, 4); s += __shfl_xor(s, 8);
        run[i] = s;
    }

    // cross-wave (wc) reduce via LDS, then one float per token per block
    float* sums = (float*)lds;     // 4 x 256 floats; prior barrier guarantees reuse ok
    if (cl == 0) {
        #pragma unroll
        for (int mi = 0; mi < 8; ++mi)
            #pragma unroll
            for (int r = 0; r < 4; ++r)
                sums[wc * 256 + wr * 128 + mi * 16 + khalf * 4 + r] = run[mi * 4 + r];
    }
    __syncthreads();
    if (tid < 256) {
        float S = sums[tid] + sums[256 + tid] + sums[512 + tid] + sums[768 + tid];
        pairs[(size_t)nc * NTOK + tok0 + tid] = S;
    }
}

// ---------------------------------------------------------------------------
// Combine 197 partial sums per token -> per-block loss partial sums
// ---------------------------------------------------------------------------
__global__ __launch_bounds__(256) void ce_combine(
    const float* __restrict__ pairs, const float* __restrict__ lab,
    float* __restrict__ partials)
{
    int t = blockIdx.x * 256 + threadIdx.x;    // grid 16 x 256 = 4096 tokens
    float S = 0.f;
    for (int c = 0; c < NC; ++c) S += pairs[(size_t)c * NTOK + t];
    float acc = log2f(S) * LN2F - lab[t];
    #pragma unroll
    for (int off = 32; off; off >>= 1) acc += __shfl_down(acc, off, 64);
    __shared__ float red[4];
    if ((threadIdx.x & 63) == 0) red[threadIdx.x >> 6] = acc;
    __syncthreads();
    if (threadIdx.x == 0)
        partials[blockIdx.x] = red[0] + red[1] + red[2] + red[3];
}

__global__ void ce_sum(const float* __restrict__ partials, float* __restrict__ out) {
    if (threadIdx.x == 0) {
        float s = 0.f;
        for (int i = 0; i < 16; ++i) s += partials[i];
        out[0] = s / (float)NTOK;
    }
}

// ---------------------------------------------------------------------------
// FALLBACK path (round-1 fp32 kernels) — used only if ws_size is too small
// ---------------------------------------------------------------------------
__global__ __launch_bounds__(256) void ce_partial_old(
    const float* __restrict__ X, const float* __restrict__ E,
    const float* __restrict__ bias, float* __restrict__ pairs)
{
    int ttile = blockIdx.x;
    int chunk = blockIdx.y;
    int tid = threadIdx.x;
    int ty = tid >> 4;
    int tx = tid & 15;

    __shared__ float As_[TT][KT + 1];
    __shared__ float Bs_[VT][KT + 1];

    int tok0 = ttile * TT;
    float run_m = -INFINITY, run_s = 0.f;

    for (int sub = 0; sub < NSUB_O; ++sub) {
        int v0 = chunk * CHUNK_O + sub * VT;
        float acc[8];
        #pragma unroll
        for (int c = 0; c < 8; ++c) acc[c] = 0.f;

        for (int k0 = 0; k0 < DD; k0 += KT) {
            __syncthreads();
            {
                const float2 a2 = *(const float2*)(X + (size_t)(tok0 + ty) * DD + k0 + 2 * tx);
                As_[ty][2 * tx]     = a2.x;
                As_[ty][2 * tx + 1] = a2.y;
            }
            #pragma unroll
            for (int j = 0; j < 4; ++j) {
                int idx = tid + 256 * j;
                int r  = idx >> 3;
                int c4 = (idx & 7) << 2;
                int v = v0 + r;
                float4 b4 = make_float4(0.f, 0.f, 0.f, 0.f);
                if (v < VV)
                    b4 = *(const float4*)(E + (size_t)v * DD + k0 + c4);
                Bs_[r][c4]     = b4.x;
                Bs_[r][c4 + 1] = b4.y;
                Bs_[r][c4 + 2] = b4.z;
                Bs_[r][c4 + 3] = b4.w;
            }
            __syncthreads();
            #pragma unroll
            for (int k = 0; k < KT; ++k) {
                float a = As_[ty][k];
                #pragma unroll
                for (int c = 0; c < 8; ++c)
                    acc[c] += a * Bs_[tx + 16 * c][k];
            }
        }

        float lv[8];
        float lm = -INFINITY;
        #pragma unroll
        for (int c = 0; c < 8; ++c) {
            int v = v0 + tx + 16 * c;
            float lg = (v < VV) ? acc[c] + bias[v] : -INFINITY;
            lv[c] = lg;
            lm = fmaxf(lm, lg);
        }
        if (lm != -INFINITY) {
            float nm = fmaxf(run_m, lm);
            float s = run_s * expf(run_m - nm);
            #pragma unroll
            for (int c = 0; c < 8; ++c) s += expf(lv[c] - nm);
            run_m = nm; run_s = s;
        }
    }

    #pragma unroll
    for (int off = 1; off < 16; off <<= 1) {
        float om = __shfl_xor(run_m, off, 64);
        float os = __shfl_xor(run_s, off, 64);
        if (os > 0.f) {
            if (om > run_m) { run_s = run_s * expf(run_m - om) + os; run_m = om; }
            else            { run_s += os * expf(om - run_m); }
        }
    }
    if (tx == 0) {
        size_t o = ((size_t)chunk * NTOK + tok0 + ty) * 2;
        pairs[o]     = run_m;
        pairs[o + 1] = run_s;
    }
}

__global__ __launch_bounds__(256) void ce_final_old(
    const float* __restrict__ pairs, const float* __restrict__ lab,
    float* __restrict__ out)
{
    int tid = threadIdx.x;
    float acc = 0.f;
    for (int t = tid; t < NTOK; t += 256) {
        float M = -INFINITY, S = 0.f;
        for (int c = 0; c < NCHUNK_O; ++c) {
            size_t o = ((size_t)c * NTOK + t) * 2;
            float m = pairs[o], s = pairs[o + 1];
            if (s > 0.f) {
                if (m > M) { S = S * expf(M - m) + s; M = m; }
                else       { S += s * expf(m - M); }
            }
        }
        acc += (M + logf(S)) - lab[t];
    }
    #pragma unroll
    for (int off = 32; off; off >>= 1) acc += __shfl_down(acc, off, 64);
    __shared__ float red[4];
    if ((tid & 63) == 0) red[tid >> 6] = acc;
    __syncthreads();
    if (tid == 0)
        out[0] = (red[0] + red[1] + red[2] + red[3]) / (float)NTOK;
}

// ---------------------------------------------------------------------------
extern "C" void kernel_launch(void* const* d_in, const int* in_sizes, int n_in,
                              void* d_out, int out_size, void* d_ws, size_t ws_size,
                              hipStream_t stream) {
    const float* X      = (const float*)d_in[0];   // [4096,1024]
    const float* E      = (const float*)d_in[1];   // [50257,1024]
    const float* bias   = (const float*)d_in[2];   // [50257]
    const int*   labels = (const int*)d_in[3];     // [4096]
    float* out = (float*)d_out;

    char* ws = (char*)d_ws;
    const size_t off_lab   = 0;                                  // 16 KB
    const size_t off_pairs = 16384;
    const size_t sz_pairs  = (size_t)NC * NTOK * 4;              // ~3.2 MB
    const size_t off_part  = off_pairs + sz_pairs;               // 3244032
    const size_t off_Xb    = off_part + 1024;                    // 16B aligned
    const size_t off_Eb    = off_Xb + (size_t)NTOK * DD * 2;
    const size_t need      = off_Eb + (size_t)VPAD * DD * 2;     // ~110 MB

    float* lab = (float*)(ws + off_lab);

    if (ws_size >= need) {
        unsigned short* Xb = (unsigned short*)(ws + off_Xb);
        unsigned short* Eb = (unsigned short*)(ws + off_Eb);
        float* pairs    = (float*)(ws + off_pairs);
        float* partials = (float*)(ws + off_part);

        convX<<<NTOK * DD / 1024, 256, 0, stream>>>(X, Xb);
        convE<<<VPAD, 256, 0, stream>>>(E, Eb);
        ce_label<<<NTOK, 256, 0, stream>>>(X, E, bias, labels, lab);
        dim3 grid(NMT, NC);
        ce_mfma256<<<grid, 512, 0, stream>>>(Xb, Eb, bias, pairs);
        ce_combine<<<16, 256, 0, stream>>>(pairs, lab, partials);
        ce_sum<<<1, 64, 0, stream>>>(partials, out);
    } else {
        float* pairs = (float*)(ws + 16384);
        ce_label<<<NTOK, 256, 0, stream>>>(X, E, bias, labels, lab);
        dim3 grid(NTTILE_O, NCHUNK_O);
        ce_partial_old<<<grid, 256, 0, stream>>>(X, E, bias, pairs);
        ce_final_old<<<1, 256, 0, stream>>>(pairs, lab, out);
    }
}